// Round 1
// baseline (442.951 us; speedup 1.0000x reference)
//
#include <hip/hip_runtime.h>

// ---------------------------------------------------------------------------
// CMSFlipLinear: y = x @ W^T, W = ternary * per-128-group scales.
// Strategy: dequantize W -> bf16, convert x -> bf16, then bf16 MFMA GEMM
// (m97 structure: 128x128 tile, BK=32, global_load_lds width 16, 4 waves).
// M = 8192 (4*2048), N = 4096 (out), K = 4096 (in). All divisible by tiles.
// ---------------------------------------------------------------------------

using bf16x8 = __attribute__((ext_vector_type(8))) short;
using f32x4  = __attribute__((ext_vector_type(4))) float;
using u16x4  = __attribute__((ext_vector_type(4))) unsigned short;
using u16x8  = __attribute__((ext_vector_type(8))) unsigned short;

constexpr int K = 4096;
constexpr int N = 4096;

__device__ __forceinline__ unsigned short f2bf(float f) {
  // round-to-nearest-even fp32 -> bf16 (bit trick)
  unsigned u = __float_as_uint(f);
  u += 0x7FFFu + ((u >> 16) & 1u);
  return (unsigned short)(u >> 16);
}

// async global->LDS, 16B per lane. LDS dest is wave-uniform base + lane*16.
__device__ __forceinline__ void gload_lds16(const void* gsrc, void* ldst) {
  const __attribute__((address_space(1))) unsigned* g =
      reinterpret_cast<const __attribute__((address_space(1))) unsigned*>(
          reinterpret_cast<uintptr_t>(gsrc));
  __attribute__((address_space(3))) unsigned* l =
      reinterpret_cast<__attribute__((address_space(3))) unsigned*>(
          reinterpret_cast<uintptr_t>(ldst));
  __builtin_amdgcn_global_load_lds(g, l, 16, 0, 0);
}

// ---- prep 1: x fp32 -> bf16 ------------------------------------------------
__global__ void cvt_x_kernel(const float* __restrict__ x,
                             unsigned short* __restrict__ o, long n4) {
  long t = (long)blockIdx.x * blockDim.x + threadIdx.x;
  if (t >= n4) return;
  float4 v = reinterpret_cast<const float4*>(x)[t];
  u16x4 r = {f2bf(v.x), f2bf(v.y), f2bf(v.z), f2bf(v.w)};
  reinterpret_cast<u16x4*>(o)[t] = r;
}

// ---- prep 2: W = ternary * scales -> bf16 ---------------------------------
__global__ void dequant_kernel(const int* __restrict__ w,
                               const float* __restrict__ s,
                               unsigned short* __restrict__ o, long n8) {
  long t = (long)blockIdx.x * blockDim.x + threadIdx.x;
  if (t >= n8) return;
  long e = t * 8;                      // 8 consecutive weights, same group
  float sc = s[e >> 7];                // group = flat / 128
  int4 a = reinterpret_cast<const int4*>(w + e)[0];
  int4 b = reinterpret_cast<const int4*>(w + e)[1];
  u16x8 r = {f2bf((float)a.x * sc), f2bf((float)a.y * sc),
             f2bf((float)a.z * sc), f2bf((float)a.w * sc),
             f2bf((float)b.x * sc), f2bf((float)b.y * sc),
             f2bf((float)b.z * sc), f2bf((float)b.w * sc)};
  *reinterpret_cast<u16x8*>(o + e) = r;
}

// ---- bf16 GEMM: C[M][N] = A[M][K] * B[N][K]^T ------------------------------
// 128x128 block tile, BK=32, 256 threads (4 waves, 2x2), each wave 64x64
// output as 4x4 fragments of mfma_f32_16x16x32_bf16.
__global__ __launch_bounds__(256) void gemm_kernel(
    const short* __restrict__ A, const short* __restrict__ B,
    float* __restrict__ C) {
  __shared__ __align__(16) short As[128][32];
  __shared__ __align__(16) short Bs[128][32];

  const int tid = threadIdx.x;
  const int w = tid >> 6;        // wave 0..3
  const int l = tid & 63;        // lane
  const int wr = w >> 1;         // wave row (0..1)
  const int wc = w & 1;          // wave col (0..1)
  const long brow = (long)blockIdx.y * 128;
  const long bcol = (long)blockIdx.x * 128;

  // staging decomposition: tile is 8 chunks of 16 rows x 32 cols (1024 B).
  // chunk c = i*4 + w; within a chunk lane l covers row c*16 + l/4,
  // cols (l%4)*8 .. +8  (16 B) — matches LDS linear order base + l*16.
  const int srow = l >> 2;
  const int scol = (l & 3) * 8;
  const short* gA0 = A + (brow + srow) * (long)K + scol;
  const short* gB0 = B + (bcol + srow) * (long)K + scol;

  f32x4 acc[4][4] = {};

  for (int k0 = 0; k0 < K; k0 += 32) {
#pragma unroll
    for (int i = 0; i < 2; ++i) {
      const int c = i * 4 + w;
      gload_lds16(gA0 + (long)(c * 16) * K + k0, &As[0][0] + c * 512);
      gload_lds16(gB0 + (long)(c * 16) * K + k0, &Bs[0][0] + c * 512);
    }
    __syncthreads();  // compiler drains vmcnt(0) before barrier

    const int rlo = l & 15;
    const int kb = (l >> 4) * 8;
    bf16x8 af[4], bfr[4];
#pragma unroll
    for (int mi = 0; mi < 4; ++mi)
      af[mi] = *reinterpret_cast<const bf16x8*>(&As[wr * 64 + mi * 16 + rlo][kb]);
#pragma unroll
    for (int ni = 0; ni < 4; ++ni)
      bfr[ni] = *reinterpret_cast<const bf16x8*>(&Bs[wc * 64 + ni * 16 + rlo][kb]);
#pragma unroll
    for (int mi = 0; mi < 4; ++mi)
#pragma unroll
      for (int ni = 0; ni < 4; ++ni)
        acc[mi][ni] = __builtin_amdgcn_mfma_f32_16x16x32_bf16(
            af[mi], bfr[ni], acc[mi][ni], 0, 0, 0);
    __syncthreads();  // protect LDS before next stage
  }

  // epilogue: C/D layout col = lane&15, row = (lane>>4)*4 + reg  (m89-verified)
  float* Cw = C + (brow + wr * 64 + (l >> 4) * 4) * (long)N + bcol + wc * 64 + (l & 15);
#pragma unroll
  for (int mi = 0; mi < 4; ++mi)
#pragma unroll
    for (int ni = 0; ni < 4; ++ni)
#pragma unroll
      for (int r = 0; r < 4; ++r)
        Cw[(long)(mi * 16 + r) * N + ni * 16] = acc[mi][ni][r];
}

// ---- fallback (only if workspace too small): naive fp32 --------------------
__global__ void fallback_kernel(const float* __restrict__ x,
                                const int* __restrict__ t,
                                const float* __restrict__ s,
                                float* __restrict__ y) {
  int n = blockIdx.x * 256 + threadIdx.x;
  int m = blockIdx.y;
  const int* tr = t + (long)n * K;
  const float* xr = x + (long)m * K;
  float acc = 0.f;
  for (int g = 0; g < K / 128; ++g) {
    float sc = s[n * (K / 128) + g];
    float part = 0.f;
#pragma unroll 4
    for (int k = g * 128; k < g * 128 + 128; ++k)
      part += xr[k] * (float)tr[k];
    acc += part * sc;
  }
  y[(long)m * N + n] = acc;
}

extern "C" void kernel_launch(void* const* d_in, const int* in_sizes, int n_in,
                              void* d_out, int out_size, void* d_ws,
                              size_t ws_size, hipStream_t stream) {
  const float* x = (const float*)d_in[0];
  const int* tern = (const int*)d_in[1];
  const float* scales = (const float*)d_in[2];
  float* out = (float*)d_out;

  const long M = (long)in_sizes[0] / K;  // 8192
  const size_t needA = (size_t)M * K * sizeof(short);      // 64 MiB
  const size_t needB = (size_t)N * K * sizeof(short);      // 32 MiB

  if (ws_size >= needA + needB) {
    short* Abf = (short*)d_ws;
    short* Bbf = (short*)((char*)d_ws + needA);

    long n4 = M * K / 4;
    cvt_x_kernel<<<(unsigned)((n4 + 255) / 256), 256, 0, stream>>>(
        x, (unsigned short*)Abf, n4);

    long n8 = (long)N * K / 8;
    dequant_kernel<<<(unsigned)((n8 + 255) / 256), 256, 0, stream>>>(
        tern, scales, (unsigned short*)Bbf, n8);

    dim3 grid(N / 128, (unsigned)(M / 128));
    gemm_kernel<<<grid, 256, 0, stream>>>(Abf, Bbf, out);
  } else {
    dim3 grid(N / 256, (unsigned)M);
    fallback_kernel<<<grid, 256, 0, stream>>>(x, tern, scales, out);
  }
}

// Round 2
// 280.435 us; speedup vs baseline: 1.5795x; 1.5795x over previous
//
#include <hip/hip_runtime.h>

// ---------------------------------------------------------------------------
// CMSFlipLinear: y = x @ W^T, W = ternary * per-128-group scales.
// Round 2: 256x256 8-phase bf16 GEMM (m201 template: T1 XCD swizzle,
// T2 (row&7)<<4 LDS XOR swizzle both-sides, T3/T4 counted vmcnt(6),
// T5 setprio around MFMA clusters). M=8192, N=4096, K=4096.
// ---------------------------------------------------------------------------

using bf16x8 = __attribute__((ext_vector_type(8))) short;
using f32x4  = __attribute__((ext_vector_type(4))) float;
using u16x4  = __attribute__((ext_vector_type(4))) unsigned short;
using u16x8  = __attribute__((ext_vector_type(8))) unsigned short;

constexpr int K = 4096;
constexpr int N = 4096;

__device__ __forceinline__ unsigned short f2bf(float f) {
  unsigned u = __float_as_uint(f);
  u += 0x7FFFu + ((u >> 16) & 1u);
  return (unsigned short)(u >> 16);
}

__device__ __forceinline__ void gload_lds16(const void* gsrc, void* ldst) {
  const __attribute__((address_space(1))) unsigned* g =
      reinterpret_cast<const __attribute__((address_space(1))) unsigned*>(
          reinterpret_cast<uintptr_t>(gsrc));
  __attribute__((address_space(3))) unsigned* l =
      reinterpret_cast<__attribute__((address_space(3))) unsigned*>(
          reinterpret_cast<uintptr_t>(ldst));
  __builtin_amdgcn_global_load_lds(g, l, 16, 0, 0);
}

// ---- prep 1: x fp32 -> bf16 ------------------------------------------------
__global__ void cvt_x_kernel(const float* __restrict__ x,
                             unsigned short* __restrict__ o, long n4) {
  long t = (long)blockIdx.x * blockDim.x + threadIdx.x;
  if (t >= n4) return;
  float4 v = reinterpret_cast<const float4*>(x)[t];
  u16x4 r = {f2bf(v.x), f2bf(v.y), f2bf(v.z), f2bf(v.w)};
  reinterpret_cast<u16x4*>(o)[t] = r;
}

// ---- prep 2: W = ternary * scales -> bf16 ---------------------------------
__global__ void dequant_kernel(const int* __restrict__ w,
                               const float* __restrict__ s,
                               unsigned short* __restrict__ o, long n8) {
  long t = (long)blockIdx.x * blockDim.x + threadIdx.x;
  if (t >= n8) return;
  long e = t * 8;
  float sc = s[e >> 7];
  int4 a = reinterpret_cast<const int4*>(w + e)[0];
  int4 b = reinterpret_cast<const int4*>(w + e)[1];
  u16x8 r = {f2bf((float)a.x * sc), f2bf((float)a.y * sc),
             f2bf((float)a.z * sc), f2bf((float)a.w * sc),
             f2bf((float)b.x * sc), f2bf((float)b.y * sc),
             f2bf((float)b.z * sc), f2bf((float)b.w * sc)};
  *reinterpret_cast<u16x8*>(o + e) = r;
}

// ---------------------------------------------------------------------------
// 8-phase GEMM helpers
// ---------------------------------------------------------------------------
// LDS layout (shorts): As0 [0,16384) | Bs0 [16384,32768) | As1 [32768,49152)
//                      | Bs1 [49152,65536).  Region bases 64KiB/32KiB aligned
// so the (row&7)<<4-byte XOR swizzle can be applied on local offsets.
// Swizzle (shorts): idx = row*64 + (col ^ ((row&7)<<3)).  Involution; applied
// on the ds_read side AND (inverse = same) on the global source of the
// linear-dest global_load_lds (rule #21: both-sides-or-neither).

__device__ __forceinline__ bf16x8 ldfrag(const short* region, int row, int col) {
  return *reinterpret_cast<const bf16x8*>(region + row * 64 +
                                          (col ^ ((row & 7) << 3)));
}

// Stage one half-tile (128 rows x 64 cols bf16 = 16 KiB) of matrix `gmat`
// (base = matrix + tile_row0*K) at K-offset k0, half h, into LDS region.
// 2 global_load_lds_dwordx4 per thread (512 thr x 16 B x 2 = 16 KiB).
// LDS dest linear; global source pre-swizzled to match ldfrag's XOR.
__device__ __forceinline__ void stage_half(const short* gmat, short* lregion,
                                           int k0, int h, int wid, int l) {
#pragma unroll
  for (int load = 0; load < 2; ++load) {
    const int row = h * 128 + load * 64 + wid * 8 + (l >> 3);
    const int col = ((l & 7) ^ (l >> 3)) << 3;   // inverse-swizzled source col
    const short* g = gmat + (long)row * K + k0 + col;
    short* ldst = lregion + h * 8192 + load * 4096 + wid * 512;  // wave-uniform
    gload_lds16(g, ldst);
  }
}

template <int M0, int M1>
__device__ __forceinline__ void loadA(bf16x8 (&afr)[8][2], const short* ar,
                                      int wr, int rlo, int kq) {
#pragma unroll
  for (int mi = M0; mi < M1; ++mi)
#pragma unroll
    for (int kk = 0; kk < 2; ++kk)
      afr[mi][kk] = ldfrag(ar, wr * 128 + mi * 16 + rlo, kk * 32 + kq * 8);
}

__device__ __forceinline__ void loadB(bf16x8 (&bfr)[4][2], const short* br,
                                      int wc, int rlo, int kq) {
#pragma unroll
  for (int ni = 0; ni < 4; ++ni)
#pragma unroll
    for (int kk = 0; kk < 2; ++kk)
      bfr[ni][kk] = ldfrag(br, wc * 64 + ni * 16 + rlo, kk * 32 + kq * 8);
}

template <int Q>
__device__ __forceinline__ void mmaQ(f32x4 (&acc)[8][4], bf16x8 (&afr)[8][2],
                                     bf16x8 (&bfr)[4][2]) {
  __builtin_amdgcn_s_setprio(1);
#pragma unroll
  for (int m = 2 * Q; m < 2 * Q + 2; ++m)
#pragma unroll
    for (int ni = 0; ni < 4; ++ni)
#pragma unroll
      for (int kk = 0; kk < 2; ++kk)
        acc[m][ni] = __builtin_amdgcn_mfma_f32_16x16x32_bf16(
            afr[m][kk], bfr[ni][kk], acc[m][ni], 0, 0, 0);
  __builtin_amdgcn_s_setprio(0);
}

#define FENCE asm volatile("" ::: "memory")
#define BAR            \
  do {                 \
    __builtin_amdgcn_s_barrier(); \
    FENCE;             \
  } while (0)
#define LGKM0 asm volatile("s_waitcnt lgkmcnt(0)" ::: "memory")
#define VMCNT6 asm volatile("s_waitcnt vmcnt(6)" ::: "memory")
#define VMCNT0 asm volatile("s_waitcnt vmcnt(0)" ::: "memory")

// ---- 256x256 8-phase GEMM: C[M][N] = A[M][K] * B[N][K]^T -------------------
// 8 waves (2M x 4N), per-wave output 128x64 = acc[8][4] f32x4.
// Stage<->read phase map (provably race-free: every stage targets a region
// whose last ds_read drained >= 1 barrier earlier):
//   P1: rd B(all)+A q0 | st t+1 A-hi   P5: rd B+A q0 (buf^1) | st t+2 A-hi
//   P2: rd A q1,q2     | st t+2 B-lo   P6: rd A q1,q2        | st t+3 B-lo
//   P3: rd A q3        | st t+2 B-hi   P7: rd A q3           | st t+3 B-hi
//   P4: mma q3, vmcnt6 | st t+2 A-lo   P8: mma q3, vmcnt6    | st t+3 A-lo
__global__ __launch_bounds__(512) void gemm8p(const short* __restrict__ A,
                                              const short* __restrict__ B,
                                              float* __restrict__ C) {
  __shared__ short lds[65536];  // 128 KiB
  const int tid = threadIdx.x;
  const int wid = tid >> 6, l = tid & 63;
  const int wr = wid >> 2, wc = wid & 3;
  const int rlo = l & 15, kq = l >> 4;

  // T1: bijective XCD swizzle (512 blocks, 512%8==0)
  const int wg = blockIdx.x;
  const int swz = (wg & 7) * 64 + (wg >> 3);
  const long brow = (long)(swz >> 4) * 256;  // M-tile (32 of them)
  const long bcol = (long)(swz & 15) * 256;  // N-tile (16 of them)

  const short* gA = A + brow * K;
  const short* gB = B + bcol * K;
  short* a0 = lds;
  short* b0 = lds + 16384;
  short* a1 = lds + 32768;
  short* b1 = lds + 49152;

  // prologue: tile0 (buf0) all 4 halves + tile1 (buf1) first 3 halves
  stage_half(gB, b0, 0, 0, wid, l);
  stage_half(gB, b0, 0, 1, wid, l);
  stage_half(gA, a0, 0, 0, wid, l);
  stage_half(gA, a0, 0, 1, wid, l);
  stage_half(gB, b1, 64, 0, wid, l);
  stage_half(gB, b1, 64, 1, wid, l);
  stage_half(gA, a1, 64, 0, wid, l);
  VMCNT6;  // tile0 complete; tile1 {B-lo,B-hi,A-lo} in flight
  BAR;

  f32x4 acc[8][4] = {};
  bf16x8 afr[8][2], bfr[4][2];

#pragma unroll 1
  for (int it = 0; it < 31; ++it) {
    const int k1 = (2 * it + 1) * 64, k2 = k1 + 64, k3 = k2 + 64;
    // ---- tile 2it (buf0) ----
    // P1
    loadB(bfr, b0, wc, rlo, kq);
    loadA<0, 2>(afr, a0, wr, rlo, kq);
    stage_half(gA, a1, k1, 1, wid, l);  // tile 2it+1 A-hi
    BAR; LGKM0;
    mmaQ<0>(acc, afr, bfr);
    BAR;
    // P2
    loadA<2, 6>(afr, a0, wr, rlo, kq);
    stage_half(gB, b0, k2, 0, wid, l);  // tile 2it+2 B-lo (B drained @P1)
    BAR; LGKM0;
    mmaQ<1>(acc, afr, bfr);
    BAR;
    // P3
    loadA<6, 8>(afr, a0, wr, rlo, kq);
    stage_half(gB, b0, k2, 1, wid, l);
    BAR; LGKM0;
    mmaQ<2>(acc, afr, bfr);
    BAR;
    // P4
    stage_half(gA, a0, k2, 0, wid, l);  // A drained @P3
    BAR; LGKM0;
    mmaQ<3>(acc, afr, bfr);
    VMCNT6;  // tile 2it+1 now fully landed
    BAR;
    // ---- tile 2it+1 (buf1) ----
    // P5
    loadB(bfr, b1, wc, rlo, kq);
    loadA<0, 2>(afr, a1, wr, rlo, kq);
    stage_half(gA, a0, k2, 1, wid, l);  // tile 2it+2 A-hi
    BAR; LGKM0;
    mmaQ<0>(acc, afr, bfr);
    BAR;
    // P6
    loadA<2, 6>(afr, a1, wr, rlo, kq);
    stage_half(gB, b1, k3, 0, wid, l);  // tile 2it+3 B-lo
    BAR; LGKM0;
    mmaQ<1>(acc, afr, bfr);
    BAR;
    // P7
    loadA<6, 8>(afr, a1, wr, rlo, kq);
    stage_half(gB, b1, k3, 1, wid, l);
    BAR; LGKM0;
    mmaQ<2>(acc, afr, bfr);
    BAR;
    // P8
    stage_half(gA, a1, k3, 0, wid, l);
    BAR; LGKM0;
    mmaQ<3>(acc, afr, bfr);
    VMCNT6;  // tile 2it+2 now fully landed
    BAR;
  }

  // ---- epilogue: tiles 62 (buf0) + 63 (buf1) ----
  {
    loadB(bfr, b0, wc, rlo, kq);
    loadA<0, 2>(afr, a0, wr, rlo, kq);
    stage_half(gA, a1, 63 * 64, 1, wid, l);  // tile63 A-hi (last stage)
    BAR; LGKM0;
    mmaQ<0>(acc, afr, bfr);
    BAR;
    loadA<2, 6>(afr, a0, wr, rlo, kq);
    BAR; LGKM0;
    mmaQ<1>(acc, afr, bfr);
    BAR;
    loadA<6, 8>(afr, a0, wr, rlo, kq);
    BAR; LGKM0;
    mmaQ<2>(acc, afr, bfr);
    BAR;
    mmaQ<3>(acc, afr, bfr);
    VMCNT0;  // drain tile63's remaining halves
    BAR;
    // tile 63: no more LDS writers, no barriers needed
    loadB(bfr, b1, wc, rlo, kq);
    loadA<0, 8>(afr, a1, wr, rlo, kq);
    mmaQ<0>(acc, afr, bfr);
    mmaQ<1>(acc, afr, bfr);
    mmaQ<2>(acc, afr, bfr);
    mmaQ<3>(acc, afr, bfr);
  }

  // epilogue C-write: col = lane&15 (N side), row = (lane>>4)*4 + reg (M side)
  float* Cw = C + (brow + wr * 128 + kq * 4) * (long)N + bcol + wc * 64 + rlo;
#pragma unroll
  for (int mi = 0; mi < 8; ++mi)
#pragma unroll
    for (int ni = 0; ni < 4; ++ni)
#pragma unroll
      for (int r = 0; r < 4; ++r)
        Cw[(long)(mi * 16 + r) * N + ni * 16] = acc[mi][ni][r];
}

// ---- fallback (only if workspace too small): naive fp32 --------------------
__global__ void fallback_kernel(const float* __restrict__ x,
                                const int* __restrict__ t,
                                const float* __restrict__ s,
                                float* __restrict__ y) {
  int n = blockIdx.x * 256 + threadIdx.x;
  int m = blockIdx.y;
  const int* tr = t + (long)n * K;
  const float* xr = x + (long)m * K;
  float acc = 0.f;
  for (int g = 0; g < K / 128; ++g) {
    float sc = s[n * (K / 128) + g];
    float part = 0.f;
#pragma unroll 4
    for (int k = g * 128; k < g * 128 + 128; ++k)
      part += xr[k] * (float)tr[k];
    acc += part * sc;
  }
  y[(long)m * N + n] = acc;
}

extern "C" void kernel_launch(void* const* d_in, const int* in_sizes, int n_in,
                              void* d_out, int out_size, void* d_ws,
                              size_t ws_size, hipStream_t stream) {
  const float* x = (const float*)d_in[0];
  const int* tern = (const int*)d_in[1];
  const float* scales = (const float*)d_in[2];
  float* out = (float*)d_out;

  const long M = (long)in_sizes[0] / K;  // 8192
  const size_t needA = (size_t)M * K * sizeof(short);  // 64 MiB
  const size_t needB = (size_t)N * K * sizeof(short);  // 32 MiB

  if (ws_size >= needA + needB && (M % 256) == 0) {
    short* Abf = (short*)d_ws;
    short* Bbf = (short*)((char*)d_ws + needA);

    long n4 = M * K / 4;
    cvt_x_kernel<<<(unsigned)((n4 + 255) / 256), 256, 0, stream>>>(
        x, (unsigned short*)Abf, n4);

    long n8 = (long)N * K / 8;
    dequant_kernel<<<(unsigned)((n8 + 255) / 256), 256, 0, stream>>>(
        tern, scales, (unsigned short*)Bbf, n8);

    const unsigned nblk = (unsigned)((M / 256) * (N / 256));  // 512
    gemm8p<<<nblk, 512, 0, stream>>>(Abf, Bbf, out);
  } else {
    dim3 grid(N / 256, (unsigned)M);
    fallback_kernel<<<grid, 256, 0, stream>>>(x, tern, scales, out);
  }
}